// Round 3
// baseline (518.083 us; speedup 1.0000x reference)
//
#include <hip/hip_runtime.h>

#define TT 2048
#define NV 1000

// ---- XLA/Eigen f32 tanh, VERBATIM from the passing round-2 kernel. ----
// Numerics note: recurrence is contracting (R2 matched np ref to absmax 0.0
// despite different per-step rounding), but tanh's systematic bias matters
// (R1's 2sig(2x)-1 failed at 2.3e-2). DO NOT change this function.
__device__ __forceinline__ float tanh_f32(float x) {
    const float L = 7.90531110763549805f;
    x = fminf(fmaxf(x, -L), L);
    float x2 = x * x;
    float p = -2.76076847742355e-16f;
    p = __builtin_fmaf(p, x2, 2.00018790482477e-13f);
    p = __builtin_fmaf(p, x2, -8.60467152213735e-11f);
    p = __builtin_fmaf(p, x2, 5.12229709037114e-08f);
    p = __builtin_fmaf(p, x2, 1.48572235717979e-05f);
    p = __builtin_fmaf(p, x2, 6.37261928875436e-04f);
    p = __builtin_fmaf(p, x2, 4.89352455891786e-03f);
    float q = 1.19825839466702e-06f;
    q = __builtin_fmaf(q, x2, 1.18534705686654e-04f);
    q = __builtin_fmaf(q, x2, 2.26843463243900e-03f);
    q = __builtin_fmaf(q, x2, 4.89352518554385e-03f);
    float r = __builtin_amdgcn_rcpf(q);
    r = __builtin_fmaf(__builtin_fmaf(-q, r, 1.0f), r, r);  // Newton: <=1 ulp
    return (x * p) * r;
}

// DPP cross-lane (VALU, ~4 cy vs ~120 cy DS). All ctrls used are
// direction-immune: quad_perm is an explicit table; ror:4 == lane-xor4 on
// period-8 data ((q+-4) mod 8 == q^4); ror:8 == lane-xor8 mod 16.
template <int CTRL>
__device__ __forceinline__ float dppf(float x) {
    return __int_as_float(__builtin_amdgcn_update_dpp(
        0, __float_as_int(x), CTRL, 0xF, 0xF, true));
}
#define DPP_XOR1 0xB1   // quad_perm [1,0,3,2]
#define DPP_XOR2 0x4E   // quad_perm [2,3,0,1]
#define DPP_XOR3 0x1B   // quad_perm [3,2,1,0]
#define DPP_ROR4 0x124  // == lane-xor4 on period-8 data
#define DPP_ROR8 0x128  // == lane-xor8 within 16-row

template <int M>    // ds_swizzle: lane ^ M within 32-lane groups (crosses 16-row)
__device__ __forceinline__ float sxor32(float x) {
    return __int_as_float(__builtin_amdgcn_ds_swizzle(__float_as_int(x), (M << 10) | 0x1f));
}

// LDS: TAB[1000][32] f32 = s_g*(W_ih.emb[v] + b_ih + b_hh), s_g=0.5 (sigmoid
// lanes, exact pow2 fold: sigma(x)=0.5+0.5*tanh(0.5x)) or 1.0 (g-gate lanes).
// 128000 B -> 1 block/CU, 512 thr = 8 waves = 2 waves/SIMD (thread-count cap).
extern "C" __global__ void __launch_bounds__(512, 2)
lstm_fused(const int* __restrict__ x, const float* __restrict__ emb,
           const float* __restrict__ W_ih, const float* __restrict__ W_hh,
           const float* __restrict__ b_ih, const float* __restrict__ b_hh,
           const float* __restrict__ W_cls, const float* __restrict__ b_cls,
           float* __restrict__ out)
{
    extern __shared__ float TAB[];  // 32000 floats

    const int tid = threadIdx.x;
    const int g   = tid & 31;   // 0-7: i, 8-15: f, 16-23: g-gate, 24-31: o
    const int grp = tid >> 5;
    const int ty  = g >> 3;
    const int j   = g & 7;

    const float sc = (ty == 2) ? 1.0f : 0.5f;
    const float sa = sc;
    const float sb = (ty == 2) ? 0.0f : 0.5f;
    const bool  b0 = (ty & 1) != 0;   // compares hoisted; loop body = cndmask only
    const bool  b1 = (ty & 2) != 0;

    // ---- phase 1: TAB[v][g] (lane g -> bank g, conflict-free) — unchanged ----
    {
        float wi[8];
        #pragma unroll
        for (int k = 0; k < 8; ++k) wi[k] = W_ih[g * 8 + k];
        const float bs = b_ih[g] + b_hh[g];
        for (int v = grp; v < NV; v += 16) {
            const float4 e0 = *(const float4*)(emb + v * 8);
            const float4 e1 = *(const float4*)(emb + v * 8 + 4);
            float d = bs + e0.x * wi[0] + e0.y * wi[1] + e0.z * wi[2] + e0.w * wi[3]
                         + e1.x * wi[4] + e1.y * wi[5] + e1.z * wi[6] + e1.w * wi[7];
            TAB[v * 32 + g] = sc * d;
        }
    }
    __syncthreads();

    // ---- recurrence: 32 lanes/row; h & c replicated on all 4 lanes of a unit ----
    const int b = blockIdx.x * 16 + grp;
    const int* __restrict__ xrow = x + (size_t)b * TT;

    // wx[m] pairs with h_{j^m} (xor-ordered dot; same products as linear order,
    // reordered sum — safe per contraction evidence from R2's absmax 0.0)
    float wx[8];
    #pragma unroll
    for (int m = 0; m < 8; ++m) wx[m] = sc * W_hh[g * 8 + (j ^ m)];

    float c  = 0.0f;
    float hn = 0.0f;   // every lane: h_{g&7} (replicated across gate types)

    int4 iA = *(const int4*)(xrow);
    int4 iB = *(const int4*)(xrow + 4);
    float xg0 = TAB[iA.x * 32 + g];   // depth-2 TAB prefetch pipeline
    float xg1 = TAB[iA.y * 32 + g];

#define STEP(XG, NIDX) do {                                                      \
        /* u = XG + sum_k sc*W_hh[g][k]*h_k via xor-indexed DPP, 2 fma chains */ \
        float v1 = dppf<DPP_XOR1>(hn);                                           \
        float v2 = dppf<DPP_XOR2>(hn);                                           \
        float v3 = dppf<DPP_XOR3>(hn);                                           \
        float v4 = dppf<DPP_ROR4>(hn);                                           \
        float uA = __builtin_fmaf(wx[0], hn, XG);                                \
        float uB = wx[1] * v1;                                                   \
        float v5 = dppf<DPP_XOR1>(v4);                                           \
        float v6 = dppf<DPP_XOR2>(v4);                                           \
        float v7 = dppf<DPP_XOR3>(v4);                                           \
        uA = __builtin_fmaf(wx[2], v2, uA);                                      \
        uB = __builtin_fmaf(wx[3], v3, uB);                                      \
        uA = __builtin_fmaf(wx[4], v4, uA);                                      \
        uB = __builtin_fmaf(wx[5], v5, uB);                                      \
        uA = __builtin_fmaf(wx[6], v6, uA);                                      \
        uB = __builtin_fmaf(wx[7], v7, uB);                                      \
        float u = uA + uB;                                                       \
        XG = TAB[(NIDX) * 32 + g];              /* prefetch for step t+2 */      \
        float act = __builtin_fmaf(sa, tanh_f32(u), sb);                         \
        float a16 = sxor32<16>(act);            /* DS — the one trip, issue 1st */\
        float a24 = sxor32<24>(act);            /* DS (pipelined with a16) */    \
        float a8  = dppf<DPP_ROR8>(act);        /* xor8 via DPP */               \
        /* quartet a_m = act of gate-type ty^m; route I*G, F, O via ty bits */   \
        float ig  = b0 ? (a8 * a24) : (act * a16);   /* sig(i)*tanh(g) */        \
        float u01 = b0 ? act : a8;                                               \
        float u23 = b0 ? a16 : a24;                                              \
        float F   = b1 ? u23 : u01;             /* sig(f) */                     \
        float O   = b1 ? u01 : u23;             /* sig(o) */                     \
        c  = __builtin_fmaf(F, c, ig);                                           \
        hn = O * tanh_f32(c);                                                    \
    } while (0)

    for (int t = 0; t < TT; t += 4) {
        const int nb = (t + 8 < TT) ? (t / 4 + 2) : 0;  // clamp tail prefetch
        int4 iN = *(const int4*)(xrow + nb * 4);
        STEP(xg0, iA.z);
        STEP(xg1, iA.w);
        STEP(xg0, iB.x);
        STEP(xg1, iB.y);
        iA = iB; iB = iN;
    }
#undef STEP

    // ---- head: out[b] = 0.5 + 0.5*tanh(0.5*(h.W_cls + b_cls)) ----
    // lane g==0 has v_m = h_m -> same summation order as the passing R2 head.
    {
        float v1 = dppf<DPP_XOR1>(hn);
        float v2 = dppf<DPP_XOR2>(hn);
        float v3 = dppf<DPP_XOR3>(hn);
        float v4 = dppf<DPP_ROR4>(hn);
        float v5 = dppf<DPP_XOR1>(v4);
        float v6 = dppf<DPP_XOR2>(v4);
        float v7 = dppf<DPP_XOR3>(v4);
        if (g == 0) {
            float z = b_cls[0]
                + hn * W_cls[0] + v1 * W_cls[1] + v2 * W_cls[2] + v3 * W_cls[3]
                + v4 * W_cls[4] + v5 * W_cls[5] + v6 * W_cls[6] + v7 * W_cls[7];
            out[b] = __builtin_fmaf(0.5f, tanh_f32(0.5f * z), 0.5f);
        }
    }
}

extern "C" void kernel_launch(void* const* d_in, const int* in_sizes, int n_in,
                              void* d_out, int out_size, void* d_ws, size_t ws_size,
                              hipStream_t stream)
{
    (void)in_sizes; (void)n_in; (void)d_ws; (void)ws_size; (void)out_size;
    const int*   x     = (const int*)  d_in[0];
    const float* emb   = (const float*)d_in[1];
    const float* W_ih  = (const float*)d_in[2];
    const float* W_hh  = (const float*)d_in[3];
    const float* b_ih  = (const float*)d_in[4];
    const float* b_hh  = (const float*)d_in[5];
    const float* W_cls = (const float*)d_in[6];
    const float* b_cls = (const float*)d_in[7];
    float* out = (float*)d_out;

    const int lds_bytes = NV * 32 * 4;  // 128000 <= 163840 (gfx950 opt-in)
    hipFuncSetAttribute((const void*)lstm_fused,
                        hipFuncAttributeMaxDynamicSharedMemorySize, lds_bytes);

    lstm_fused<<<dim3(256), dim3(512), lds_bytes, stream>>>(
        x, emb, W_ih, W_hh, b_ih, b_hh, W_cls, b_cls, out);
}

// Round 4
// 386.092 us; speedup vs baseline: 1.3419x; 1.3419x over previous
//
#include <hip/hip_runtime.h>

#define TT 2048
#define NV 1000

// ---- XLA/Eigen f32 tanh, VERBATIM (numerics-critical; see R1 vs R2). ----
__device__ __forceinline__ float tanh_f32(float x) {
    const float L = 7.90531110763549805f;
    x = fminf(fmaxf(x, -L), L);
    float x2 = x * x;
    float p = -2.76076847742355e-16f;
    p = __builtin_fmaf(p, x2, 2.00018790482477e-13f);
    p = __builtin_fmaf(p, x2, -8.60467152213735e-11f);
    p = __builtin_fmaf(p, x2, 5.12229709037114e-08f);
    p = __builtin_fmaf(p, x2, 1.48572235717979e-05f);
    p = __builtin_fmaf(p, x2, 6.37261928875436e-04f);
    p = __builtin_fmaf(p, x2, 4.89352455891786e-03f);
    float q = 1.19825839466702e-06f;
    q = __builtin_fmaf(q, x2, 1.18534705686654e-04f);
    q = __builtin_fmaf(q, x2, 2.26843463243900e-03f);
    q = __builtin_fmaf(q, x2, 4.89352518554385e-03f);
    float r = __builtin_amdgcn_rcpf(q);
    r = __builtin_fmaf(__builtin_fmaf(-q, r, 1.0f), r, r);  // Newton: <=1 ulp
    return (x * p) * r;
}

// 2-wide tanh, statement-paired for SLP -> v_pk_* where possible.
// Each component follows tanh_f32's exact op sequence (same rounding).
__device__ __forceinline__ void tanh2_f32(float xa, float xb, float& ra, float& rb) {
    const float L = 7.90531110763549805f;
    xa = fminf(fmaxf(xa, -L), L);          xb = fminf(fmaxf(xb, -L), L);
    float a2 = xa * xa;                    float b2 = xb * xb;
    float pa = -2.76076847742355e-16f;     float pb = -2.76076847742355e-16f;
    pa = __builtin_fmaf(pa, a2, 2.00018790482477e-13f);  pb = __builtin_fmaf(pb, b2, 2.00018790482477e-13f);
    pa = __builtin_fmaf(pa, a2, -8.60467152213735e-11f); pb = __builtin_fmaf(pb, b2, -8.60467152213735e-11f);
    pa = __builtin_fmaf(pa, a2, 5.12229709037114e-08f);  pb = __builtin_fmaf(pb, b2, 5.12229709037114e-08f);
    pa = __builtin_fmaf(pa, a2, 1.48572235717979e-05f);  pb = __builtin_fmaf(pb, b2, 1.48572235717979e-05f);
    pa = __builtin_fmaf(pa, a2, 6.37261928875436e-04f);  pb = __builtin_fmaf(pb, b2, 6.37261928875436e-04f);
    pa = __builtin_fmaf(pa, a2, 4.89352455891786e-03f);  pb = __builtin_fmaf(pb, b2, 4.89352455891786e-03f);
    float qa = 1.19825839466702e-06f;      float qb = 1.19825839466702e-06f;
    qa = __builtin_fmaf(qa, a2, 1.18534705686654e-04f);  qb = __builtin_fmaf(qb, b2, 1.18534705686654e-04f);
    qa = __builtin_fmaf(qa, a2, 2.26843463243900e-03f);  qb = __builtin_fmaf(qb, b2, 2.26843463243900e-03f);
    qa = __builtin_fmaf(qa, a2, 4.89352518554385e-03f);  qb = __builtin_fmaf(qb, b2, 4.89352518554385e-03f);
    float na = __builtin_amdgcn_rcpf(qa);  float nb = __builtin_amdgcn_rcpf(qb);
    na = __builtin_fmaf(__builtin_fmaf(-qa, na, 1.0f), na, na);
    nb = __builtin_fmaf(__builtin_fmaf(-qb, nb, 1.0f), nb, nb);
    ra = (xa * pa) * na;                   rb = (xb * pb) * nb;
}

// DPP cross-lane (VALU, ~4 cy). All ctrls operate within 16-lane rows:
// quad_perm = exact lane-xor{1,2,3}; row_ror:4 == xor4 on period-8 data
// (validated R3, absmax 0.0); row_ror:8 == exact xor8 within a 16-row.
template <int CTRL>
__device__ __forceinline__ float dppf(float x) {
    return __int_as_float(__builtin_amdgcn_update_dpp(
        0, __float_as_int(x), CTRL, 0xF, 0xF, true));
}
#define DPP_XOR1 0xB1   // quad_perm [1,0,3,2]
#define DPP_XOR2 0x4E   // quad_perm [2,3,0,1]
#define DPP_XOR3 0x1B   // quad_perm [3,2,1,0]
#define DPP_ROR4 0x124  // row_ror:4  == xor4 on period-8 data
#define DPP_ROR8 0x128  // row_ror:8  == xor8 within 16-row

// Layout: 16 lanes per batch row, 2 gates per lane.
//   l = (tid&15) = s*8+j;  s=0 -> gates (i_j, g_j);  s=1 -> gates (f_j, o_j)
//   lo gate index = l, hi gate index = l+16 (PyTorch i,f,g,o order).
// TAB2[v][l] = float2(0.5*pre[l], sc_hi*pre[l+16]) (sigmoid lanes pre-scaled by
// 0.5, exact pow2: sigma(x)=0.5+0.5*tanh(0.5x); g-gate sc=1). 128000 B LDS.
// Block 256 thr = 4 waves = 16 rows; grid 256 -> 1 block/CU, 1 wave/SIMD.
// All recurrence cross-lane = DPP; only TAB read uses DS (depth-2 prefetch).
extern "C" __global__ void __launch_bounds__(256, 1)
lstm_fused(const int* __restrict__ x, const float* __restrict__ emb,
           const float* __restrict__ W_ih, const float* __restrict__ W_hh,
           const float* __restrict__ b_ih, const float* __restrict__ b_hh,
           const float* __restrict__ W_cls, const float* __restrict__ b_cls,
           float* __restrict__ out)
{
    extern __shared__ float TAB[];  // float2[1000][16] viewed as float[32000]

    const int tid = threadIdx.x;
    const int l   = tid & 15;
    const int s   = l >> 3;       // 0: (i,g)-lane, 1: (f,o)-lane
    const int j   = l & 7;
    const int grp = tid >> 4;     // row within block (0..15)

    const float sc_hi = s ? 0.5f : 1.0f;   // o: sigmoid(0.5), g: tanh(1.0)
    const float sa_hi = sc_hi;
    const float sb_hi = s ? 0.5f : 0.0f;
    const bool  sf    = (s != 0);          // hoisted select bit

    // ---- phase 1: build TAB2 (lane l -> banks 2l,2l+1; 2-way aliasing free) ----
    {
        float wlo[8], whi[8];
        #pragma unroll
        for (int k = 0; k < 8; ++k) {
            wlo[k] = W_ih[l * 8 + k];
            whi[k] = W_ih[(l + 16) * 8 + k];
        }
        const float blo = b_ih[l] + b_hh[l];
        const float bhi = b_ih[l + 16] + b_hh[l + 16];
        for (int v = grp; v < NV; v += 16) {
            const float4 e0 = *(const float4*)(emb + v * 8);
            const float4 e1 = *(const float4*)(emb + v * 8 + 4);
            float dl = blo + e0.x * wlo[0] + e0.y * wlo[1] + e0.z * wlo[2] + e0.w * wlo[3]
                           + e1.x * wlo[4] + e1.y * wlo[5] + e1.z * wlo[6] + e1.w * wlo[7];
            float dh = bhi + e0.x * whi[0] + e0.y * whi[1] + e0.z * whi[2] + e0.w * whi[3]
                           + e1.x * whi[4] + e1.y * whi[5] + e1.z * whi[6] + e1.w * whi[7];
            float2* dst = (float2*)(TAB + v * 32 + l * 2);
            *dst = make_float2(0.5f * dl, sc_hi * dh);
        }
    }
    __syncthreads();

    // ---- recurrence ----
    const int b = blockIdx.x * 16 + grp;
    const int* __restrict__ xrow = x + (size_t)b * TT;

    // xor-ordered W_hh rows (pairs with DPP tree output v_m = h_{j^m}; order
    // validated by R3's absmax 0.0), pre-scaled (exact pow2 for sigmoid lanes).
    float wlo[8], whi[8];
    #pragma unroll
    for (int m = 0; m < 8; ++m) {
        wlo[m] = 0.5f  * W_hh[l * 8 + (j ^ m)];
        whi[m] = sc_hi * W_hh[(l + 16) * 8 + (j ^ m)];
    }

    float c  = 0.0f;
    float hn = 0.0f;   // every lane: h_{l&7} (period-8 within 16-row)

    int4 iA = *(const int4*)(xrow);
    int4 iB = *(const int4*)(xrow + 4);
    float2 xg0 = *(const float2*)(TAB + iA.x * 32 + l * 2);  // depth-2 prefetch
    float2 xg1 = *(const float2*)(TAB + iA.y * 32 + l * 2);

#define STEP(XG, NIDX) do {                                                      \
        float v1 = dppf<DPP_XOR1>(hn);                                           \
        float v2 = dppf<DPP_XOR2>(hn);                                           \
        float v3 = dppf<DPP_XOR3>(hn);                                           \
        float v4 = dppf<DPP_ROR4>(hn);                                           \
        float uAx = __builtin_fmaf(wlo[0], hn, XG.x);                            \
        float uAy = __builtin_fmaf(whi[0], hn, XG.y);                            \
        float uBx = wlo[1] * v1;                                                 \
        float uBy = whi[1] * v1;                                                 \
        float v5 = dppf<DPP_XOR1>(v4);                                           \
        float v6 = dppf<DPP_XOR2>(v4);                                           \
        float v7 = dppf<DPP_XOR3>(v4);                                           \
        uAx = __builtin_fmaf(wlo[2], v2, uAx);  uAy = __builtin_fmaf(whi[2], v2, uAy); \
        uBx = __builtin_fmaf(wlo[3], v3, uBx);  uBy = __builtin_fmaf(whi[3], v3, uBy); \
        uAx = __builtin_fmaf(wlo[4], v4, uAx);  uAy = __builtin_fmaf(whi[4], v4, uAy); \
        uBx = __builtin_fmaf(wlo[5], v5, uBx);  uBy = __builtin_fmaf(whi[5], v5, uBy); \
        uAx = __builtin_fmaf(wlo[6], v6, uAx);  uAy = __builtin_fmaf(whi[6], v6, uAy); \
        uBx = __builtin_fmaf(wlo[7], v7, uBx);  uBy = __builtin_fmaf(whi[7], v7, uBy); \
        float ux = uAx + uBx;                                                    \
        float uy = uAy + uBy;                                                    \
        XG = *(const float2*)(TAB + (NIDX) * 32 + l * 2);  /* prefetch t+2 */    \
        float tl, th_;                                                           \
        tanh2_f32(ux, uy, tl, th_);                                              \
        float aLo = __builtin_fmaf(0.5f,  tl,  0.5f);   /* sigma(i) or sigma(f) */ \
        float aHi = __builtin_fmaf(sa_hi, th_, sb_hi);  /* tanh(g) or sigma(o) */  \
        float pLo = dppf<DPP_ROR8>(aLo);                /* partner's lo */       \
        float pHi = dppf<DPP_ROR8>(aHi);                /* partner's hi */       \
        float I = sf ? pLo : aLo;                                                \
        float G = sf ? pHi : aHi;                                                \
        float F = sf ? aLo : pLo;                                                \
        float O = sf ? aHi : pHi;                                                \
        c  = __builtin_fmaf(F, c, I * G);                                        \
        hn = O * tanh_f32(c);                                                    \
    } while (0)

    for (int t = 0; t < TT; t += 4) {
        const int nb = (t + 8 < TT) ? (t / 4 + 2) : 0;  // clamp tail prefetch
        int4 iN = *(const int4*)(xrow + nb * 4);
        STEP(xg0, iA.z);
        STEP(xg1, iA.w);
        STEP(xg0, iB.x);
        STEP(xg1, iB.y);
        iA = iB; iB = iN;
    }
#undef STEP

    // ---- head: out[b] = 0.5 + 0.5*tanh(0.5*(h.W_cls + b_cls)) ----
    // On lane l==0: hn=h_0, v_m=h_m -> same summation order as passing R2/R3.
    {
        float v1 = dppf<DPP_XOR1>(hn);
        float v2 = dppf<DPP_XOR2>(hn);
        float v3 = dppf<DPP_XOR3>(hn);
        float v4 = dppf<DPP_ROR4>(hn);
        float v5 = dppf<DPP_XOR1>(v4);
        float v6 = dppf<DPP_XOR2>(v4);
        float v7 = dppf<DPP_XOR3>(v4);
        if (l == 0) {
            float z = b_cls[0]
                + hn * W_cls[0] + v1 * W_cls[1] + v2 * W_cls[2] + v3 * W_cls[3]
                + v4 * W_cls[4] + v5 * W_cls[5] + v6 * W_cls[6] + v7 * W_cls[7];
            out[b] = __builtin_fmaf(0.5f, tanh_f32(0.5f * z), 0.5f);
        }
    }
}

extern "C" void kernel_launch(void* const* d_in, const int* in_sizes, int n_in,
                              void* d_out, int out_size, void* d_ws, size_t ws_size,
                              hipStream_t stream)
{
    (void)in_sizes; (void)n_in; (void)d_ws; (void)ws_size; (void)out_size;
    const int*   x     = (const int*)  d_in[0];
    const float* emb   = (const float*)d_in[1];
    const float* W_ih  = (const float*)d_in[2];
    const float* W_hh  = (const float*)d_in[3];
    const float* b_ih  = (const float*)d_in[4];
    const float* b_hh  = (const float*)d_in[5];
    const float* W_cls = (const float*)d_in[6];
    const float* b_cls = (const float*)d_in[7];
    float* out = (float*)d_out;

    const int lds_bytes = NV * 16 * 8;  // 128000 <= 163840 (gfx950 opt-in)
    hipFuncSetAttribute((const void*)lstm_fused,
                        hipFuncAttributeMaxDynamicSharedMemorySize, lds_bytes);

    lstm_fused<<<dim3(256), dim3(256), lds_bytes, stream>>>(
        x, emb, W_ih, W_hh, b_ih, b_hh, W_cls, b_cls, out);
}

// Round 5
// 385.533 us; speedup vs baseline: 1.3438x; 1.0014x over previous
//
#include <hip/hip_runtime.h>

#define TT 2048
#define NV 1000

typedef float v2f __attribute__((ext_vector_type(2)));

static __device__ __forceinline__ v2f sp(float x) { return (v2f){x, x}; }
static __device__ __forceinline__ v2f pkfma(v2f a, v2f b, v2f c) {
    return __builtin_elementwise_fma(a, b, c);
}

// ---- XLA/Eigen f32 tanh, scalar, VERBATIM (numerics-critical; R1 vs R2). ----
__device__ __forceinline__ float tanh_f32(float x) {
    const float L = 7.90531110763549805f;
    x = fminf(fmaxf(x, -L), L);
    float x2 = x * x;
    float p = -2.76076847742355e-16f;
    p = __builtin_fmaf(p, x2, 2.00018790482477e-13f);
    p = __builtin_fmaf(p, x2, -8.60467152213735e-11f);
    p = __builtin_fmaf(p, x2, 5.12229709037114e-08f);
    p = __builtin_fmaf(p, x2, 1.48572235717979e-05f);
    p = __builtin_fmaf(p, x2, 6.37261928875436e-04f);
    p = __builtin_fmaf(p, x2, 4.89352455891786e-03f);
    float q = 1.19825839466702e-06f;
    q = __builtin_fmaf(q, x2, 1.18534705686654e-04f);
    q = __builtin_fmaf(q, x2, 2.26843463243900e-03f);
    q = __builtin_fmaf(q, x2, 4.89352518554385e-03f);
    float r = __builtin_amdgcn_rcpf(q);
    r = __builtin_fmaf(__builtin_fmaf(-q, r, 1.0f), r, r);  // Newton: <=1 ulp
    return (x * p) * r;
}

// Packed 2-wide tanh: per-component op sequence IDENTICAL to tanh_f32
// (v_pk_fma_f32 rounds each half exactly like v_fma_f32).
__device__ __forceinline__ v2f tanh2p(v2f x) {
    const float L = 7.90531110763549805f;
    x = __builtin_elementwise_min(__builtin_elementwise_max(x, sp(-L)), sp(L));
    v2f x2 = x * x;
    v2f p = sp(-2.76076847742355e-16f);
    p = pkfma(p, x2, sp(2.00018790482477e-13f));
    p = pkfma(p, x2, sp(-8.60467152213735e-11f));
    p = pkfma(p, x2, sp(5.12229709037114e-08f));
    p = pkfma(p, x2, sp(1.48572235717979e-05f));
    p = pkfma(p, x2, sp(6.37261928875436e-04f));
    p = pkfma(p, x2, sp(4.89352455891786e-03f));
    v2f q = sp(1.19825839466702e-06f);
    q = pkfma(q, x2, sp(1.18534705686654e-04f));
    q = pkfma(q, x2, sp(2.26843463243900e-03f));
    q = pkfma(q, x2, sp(4.89352518554385e-03f));
    v2f r = { __builtin_amdgcn_rcpf(q.x), __builtin_amdgcn_rcpf(q.y) };
    r = pkfma(pkfma(-q, r, sp(1.0f)), r, r);
    return (x * p) * r;
}

// DPP cross-lane (VALU). quad_perm = exact lane-xor{1,2,3}; row_ror:4 == xor4
// on period-8 data (validated R3/R4, absmax 0.0); row_ror:8 == exact xor8.
template <int CTRL>
__device__ __forceinline__ float dppf(float x) {
    return __int_as_float(__builtin_amdgcn_update_dpp(
        0, __float_as_int(x), CTRL, 0xF, 0xF, true));
}
#define DPP_XOR1 0xB1
#define DPP_XOR2 0x4E
#define DPP_XOR3 0x1B
#define DPP_ROR4 0x124
#define DPP_ROR8 0x128

// Layout: 16 lanes per batch row. lane l = s*8+j.
//   s=0 -> gates (i_j, f_j) = indices (j, j+8)      [both sigmoid]
//   s=1 -> gates (g_j, o_j) = indices (j+16, j+24)  [tanh, sigmoid]
// Pairing (i,f)/(g,o) makes I*G = act.x * ror8(act.x) commutative-identical on
// both lanes -> only F,O need cndmask. Sigmoid lanes pre-scaled by 0.5 (exact
// pow2: sigma(x)=0.5+0.5*tanh(0.5x)); all packed math = v_pk_* VOP3P.
// TAB2[v][l] = (sc_lo*pre[glo], 0.5*pre[ghi]). 128000 B LDS -> 1 block/CU,
// 256 thr = 4 waves = 16 rows/block, grid 256 -> 1 wave/SIMD (65536 lane-slots
// == 4096 rows x 16 lanes, exact fit).
extern "C" __global__ void __launch_bounds__(256, 1)
lstm_fused(const int* __restrict__ x, const float* __restrict__ emb,
           const float* __restrict__ W_ih, const float* __restrict__ W_hh,
           const float* __restrict__ b_ih, const float* __restrict__ b_hh,
           const float* __restrict__ W_cls, const float* __restrict__ b_cls,
           float* __restrict__ out)
{
    extern __shared__ v2f TAB2[];  // [1000][16]

    const int tid = threadIdx.x;
    const int l   = tid & 15;
    const int s   = l >> 3;
    const int j   = l & 7;
    const int grp = tid >> 4;

    const int glo = j + (s << 4);   // i_j or g_j
    const int ghi = glo + 8;        // f_j or o_j
    const float sc_lo = s ? 1.0f : 0.5f;   // g: tanh(1.0); i: sigmoid(0.5)
    const v2f  saV = { s ? 1.0f : 0.5f, 0.5f };
    const v2f  sbV = { s ? 0.0f : 0.5f, 0.5f };
    const bool is0 = (s == 0);

    // ---- phase 1: build TAB2 ----
    {
        float wlo[8], whi[8];
        #pragma unroll
        for (int k = 0; k < 8; ++k) {
            wlo[k] = W_ih[glo * 8 + k];
            whi[k] = W_ih[ghi * 8 + k];
        }
        const float blo = b_ih[glo] + b_hh[glo];
        const float bhi = b_ih[ghi] + b_hh[ghi];
        for (int v = grp; v < NV; v += 16) {
            const float4 e0 = *(const float4*)(emb + v * 8);
            const float4 e1 = *(const float4*)(emb + v * 8 + 4);
            float dl = blo + e0.x * wlo[0] + e0.y * wlo[1] + e0.z * wlo[2] + e0.w * wlo[3]
                           + e1.x * wlo[4] + e1.y * wlo[5] + e1.z * wlo[6] + e1.w * wlo[7];
            float dh = bhi + e0.x * whi[0] + e0.y * whi[1] + e0.z * whi[2] + e0.w * whi[3]
                           + e1.x * whi[4] + e1.y * whi[5] + e1.z * whi[6] + e1.w * whi[7];
            TAB2[v * 16 + l] = (v2f){ sc_lo * dl, 0.5f * dh };
        }
    }
    __syncthreads();

    // ---- recurrence ----
    const int b = blockIdx.x * 16 + grp;
    const int* __restrict__ xrow = x + (size_t)b * TT;

    // xor-ordered W_hh pairs (matches DPP tree v_m = h_{j^m}; order validated
    // R3/R4 absmax 0.0), pre-scaled (exact pow2 on sigmoid lanes).
    v2f w2[8];
    #pragma unroll
    for (int m = 0; m < 8; ++m) {
        w2[m] = (v2f){ sc_lo * W_hh[glo * 8 + (j ^ m)],
                       0.5f  * W_hh[ghi * 8 + (j ^ m)] };
    }

    float c  = 0.0f;
    float hn = 0.0f;   // every lane: h_{l&7} (period-8 within 16-row)

    int4 iA = *(const int4*)(xrow);
    int4 iB = *(const int4*)(xrow + 4);
    v2f xg0 = TAB2[iA.x * 16 + l];   // depth-2 prefetch
    v2f xg1 = TAB2[iA.y * 16 + l];

#define STEP(XG, NIDX) do {                                                      \
        float v1 = dppf<DPP_XOR1>(hn);                                           \
        float v2 = dppf<DPP_XOR2>(hn);                                           \
        float v3 = dppf<DPP_XOR3>(hn);                                           \
        float v4 = dppf<DPP_ROR4>(hn);                                           \
        v2f uA = pkfma(w2[0], sp(hn), XG);                                       \
        v2f uB = w2[1] * sp(v1);                                                 \
        float v5 = dppf<DPP_XOR1>(v4);                                           \
        float v6 = dppf<DPP_XOR2>(v4);                                           \
        float v7 = dppf<DPP_XOR3>(v4);                                           \
        uA = pkfma(w2[2], sp(v2), uA);                                           \
        uB = pkfma(w2[3], sp(v3), uB);                                           \
        uA = pkfma(w2[4], sp(v4), uA);                                           \
        uB = pkfma(w2[5], sp(v5), uB);                                           \
        uA = pkfma(w2[6], sp(v6), uA);                                           \
        uB = pkfma(w2[7], sp(v7), uB);                                           \
        v2f u = uA + uB;                                                         \
        XG = TAB2[(NIDX) * 16 + l];             /* prefetch t+2 */               \
        v2f t2  = tanh2p(u);                                                     \
        v2f act = pkfma(saV, t2, sbV);  /* s0:(sig i,sig f) s1:(tanh g,sig o) */ \
        float pLo = dppf<DPP_ROR8>(act.x);                                       \
        float pHi = dppf<DPP_ROR8>(act.y);                                       \
        float IG  = act.x * pLo;        /* sig(i)*tanh(g), both lanes */         \
        float F   = is0 ? act.y : pHi;  /* sig(f) */                             \
        float O   = is0 ? pHi : act.y;  /* sig(o) */                             \
        c  = __builtin_fmaf(F, c, IG);                                           \
        hn = O * tanh_f32(c);                                                    \
    } while (0)

    for (int t = 0; t < TT; t += 4) {
        const int nb = (t + 8 < TT) ? (t / 4 + 2) : 0;  // clamp tail prefetch
        int4 iN = *(const int4*)(xrow + nb * 4);
        STEP(xg0, iA.z);
        STEP(xg1, iA.w);
        STEP(xg0, iB.x);
        STEP(xg1, iB.y);
        iA = iB; iB = iN;
    }
#undef STEP

    // ---- head: out[b] = 0.5 + 0.5*tanh(0.5*(h.W_cls + b_cls)) ----
    // Lane l==0: hn=h_0, v_m=h_m -> same summation order as passing R2-R4.
    {
        float v1 = dppf<DPP_XOR1>(hn);
        float v2 = dppf<DPP_XOR2>(hn);
        float v3 = dppf<DPP_XOR3>(hn);
        float v4 = dppf<DPP_ROR4>(hn);
        float v5 = dppf<DPP_XOR1>(v4);
        float v6 = dppf<DPP_XOR2>(v4);
        float v7 = dppf<DPP_XOR3>(v4);
        if (l == 0) {
            float z = b_cls[0]
                + hn * W_cls[0] + v1 * W_cls[1] + v2 * W_cls[2] + v3 * W_cls[3]
                + v4 * W_cls[4] + v5 * W_cls[5] + v6 * W_cls[6] + v7 * W_cls[7];
            out[b] = __builtin_fmaf(0.5f, tanh_f32(0.5f * z), 0.5f);
        }
    }
}

extern "C" void kernel_launch(void* const* d_in, const int* in_sizes, int n_in,
                              void* d_out, int out_size, void* d_ws, size_t ws_size,
                              hipStream_t stream)
{
    (void)in_sizes; (void)n_in; (void)d_ws; (void)ws_size; (void)out_size;
    const int*   x     = (const int*)  d_in[0];
    const float* emb   = (const float*)d_in[1];
    const float* W_ih  = (const float*)d_in[2];
    const float* W_hh  = (const float*)d_in[3];
    const float* b_ih  = (const float*)d_in[4];
    const float* b_hh  = (const float*)d_in[5];
    const float* W_cls = (const float*)d_in[6];
    const float* b_cls = (const float*)d_in[7];
    float* out = (float*)d_out;

    const int lds_bytes = NV * 16 * 8;  // 128000 <= 163840 (gfx950 opt-in)
    hipFuncSetAttribute((const void*)lstm_fused,
                        hipFuncAttributeMaxDynamicSharedMemorySize, lds_bytes);

    lstm_fused<<<dim3(256), dim3(256), lds_bytes, stream>>>(
        x, emb, W_ih, W_hh, b_ih, b_hh, W_cls, b_cls, out);
}

// Round 6
// 373.363 us; speedup vs baseline: 1.3876x; 1.0326x over previous
//
#include <hip/hip_runtime.h>

#define TT 2048
#define NV 1000
#define LOG2E 1.4426950408889634f

typedef float v2f __attribute__((ext_vector_type(2)));

static __device__ __forceinline__ v2f sp(float x) { return (v2f){x, x}; }
static __device__ __forceinline__ v2f pkfma(v2f a, v2f b, v2f c) {
    return __builtin_elementwise_fma(a, b, c);
}

// ---- XLA/Eigen f32 tanh, scalar, VERBATIM (numerics-critical; R1 vs R2). ----
// Used ONLY for g-gate and cell tanh (the cancellation-sensitive spots).
__device__ __forceinline__ float tanh_f32(float x) {
    const float L = 7.90531110763549805f;
    x = fminf(fmaxf(x, -L), L);
    float x2 = x * x;
    float p = -2.76076847742355e-16f;
    p = __builtin_fmaf(p, x2, 2.00018790482477e-13f);
    p = __builtin_fmaf(p, x2, -8.60467152213735e-11f);
    p = __builtin_fmaf(p, x2, 5.12229709037114e-08f);
    p = __builtin_fmaf(p, x2, 1.48572235717979e-05f);
    p = __builtin_fmaf(p, x2, 6.37261928875436e-04f);
    p = __builtin_fmaf(p, x2, 4.89352455891786e-03f);
    float q = 1.19825839466702e-06f;
    q = __builtin_fmaf(q, x2, 1.18534705686654e-04f);
    q = __builtin_fmaf(q, x2, 2.26843463243900e-03f);
    q = __builtin_fmaf(q, x2, 4.89352518554385e-03f);
    float r = __builtin_amdgcn_rcpf(q);
    r = __builtin_fmaf(__builtin_fmaf(-q, r, 1.0f), r, r);  // Newton: <=1 ulp
    return (x * p) * r;
}

// DPP cross-lane (VALU). quad_perm = exact lane-xor{1,2,3}; row_ror:4 == xor4
// on period-8 data (validated R3-R5, absmax 0.0); row_ror:8 == exact xor8.
template <int CTRL>
__device__ __forceinline__ float dppf(float x) {
    return __int_as_float(__builtin_amdgcn_update_dpp(
        0, __float_as_int(x), CTRL, 0xF, 0xF, true));
}
#define DPP_XOR1 0xB1
#define DPP_XOR2 0x4E
#define DPP_XOR3 0x1B
#define DPP_ROR4 0x124
#define DPP_ROR8 0x128

// Layout (as R5): 16 lanes per batch row, lane l = s*8+j.
//   s=0 -> gates (i_j, f_j); s=1 -> gates (g_j, o_j).
// NEW: sigmoids (i,f,o) via trans pipe: sigma(x)=rcp(1+exp2(-log2e*x)) —
// cancellation-free (1+e>=1), 1-2 ulp relative class (absorbed per R2-R5
// absmax 0.0 evidence). g and c keep R2-verbatim rational tanh. Per-slot
// prescales fold into TAB/W_hh: sigma-slots -log2e, g-slot 1.0.
// TAB2[v][l] = (sc.x*pre[glo], sc.y*pre[ghi]). 128000 B LDS -> 1 block/CU,
// 256 thr = 4 waves = 16 rows/block, grid 256 -> 1 wave/SIMD.
extern "C" __global__ void __launch_bounds__(256, 1)
lstm_fused(const int* __restrict__ x, const float* __restrict__ emb,
           const float* __restrict__ W_ih, const float* __restrict__ W_hh,
           const float* __restrict__ b_ih, const float* __restrict__ b_hh,
           const float* __restrict__ W_cls, const float* __restrict__ b_cls,
           float* __restrict__ out)
{
    extern __shared__ v2f TAB2[];  // [1000][16]

    const int tid = threadIdx.x;
    const int l   = tid & 15;
    const int s   = l >> 3;
    const int j   = l & 7;
    const int grp = tid >> 4;

    const int glo = j + (s << 4);   // i_j (s0) or g_j (s1)
    const int ghi = glo + 8;        // f_j (s0) or o_j (s1)
    const float scx = s ? 1.0f : -LOG2E;   // g: raw for rational tanh
    const float scy = -LOG2E;              // f, o: sigmoid prescale
    const bool is0 = (s == 0);
    const bool is1 = !is0;

    // ---- phase 1: build TAB2 ----
    {
        float wlo[8], whi[8];
        #pragma unroll
        for (int k = 0; k < 8; ++k) {
            wlo[k] = W_ih[glo * 8 + k];
            whi[k] = W_ih[ghi * 8 + k];
        }
        const float blo = b_ih[glo] + b_hh[glo];
        const float bhi = b_ih[ghi] + b_hh[ghi];
        for (int v = grp; v < NV; v += 16) {
            const float4 e0 = *(const float4*)(emb + v * 8);
            const float4 e1 = *(const float4*)(emb + v * 8 + 4);
            float dl = blo + e0.x * wlo[0] + e0.y * wlo[1] + e0.z * wlo[2] + e0.w * wlo[3]
                           + e1.x * wlo[4] + e1.y * wlo[5] + e1.z * wlo[6] + e1.w * wlo[7];
            float dh = bhi + e0.x * whi[0] + e0.y * whi[1] + e0.z * whi[2] + e0.w * whi[3]
                           + e1.x * whi[4] + e1.y * whi[5] + e1.z * whi[6] + e1.w * whi[7];
            TAB2[v * 16 + l] = (v2f){ scx * dl, scy * dh };
        }
    }
    __syncthreads();

    // ---- recurrence ----
    const int b = blockIdx.x * 16 + grp;
    const int* __restrict__ xrow = x + (size_t)b * TT;

    // xor-ordered W_hh pairs (matches DPP tree v_m = h_{j^m}; validated R3-R5).
    v2f w2[8];
    #pragma unroll
    for (int m = 0; m < 8; ++m) {
        w2[m] = (v2f){ scx * W_hh[glo * 8 + (j ^ m)],
                       scy * W_hh[ghi * 8 + (j ^ m)] };
    }

    float c  = 0.0f;
    float hn = 0.0f;   // every lane: h_{l&7} (period-8 within 16-row)

    int4 iA = *(const int4*)(xrow);
    int4 iB = *(const int4*)(xrow + 4);
    v2f xg0 = TAB2[iA.x * 16 + l];   // depth-2 prefetch
    v2f xg1 = TAB2[iA.y * 16 + l];

#define STEP(XG, NIDX) do {                                                      \
        float v1 = dppf<DPP_XOR1>(hn);                                           \
        float v2 = dppf<DPP_XOR2>(hn);                                           \
        float v3 = dppf<DPP_XOR3>(hn);                                           \
        float v4 = dppf<DPP_ROR4>(hn);                                           \
        v2f uA = pkfma(w2[0], sp(hn), XG);                                       \
        v2f uB = w2[1] * sp(v1);                                                 \
        float v5 = dppf<DPP_XOR1>(v4);                                           \
        float v6 = dppf<DPP_XOR2>(v4);                                           \
        float v7 = dppf<DPP_XOR3>(v4);                                           \
        uA = pkfma(w2[2], sp(v2), uA);                                           \
        uB = pkfma(w2[3], sp(v3), uB);                                           \
        uA = pkfma(w2[4], sp(v4), uA);                                           \
        uB = pkfma(w2[5], sp(v5), uB);                                           \
        uA = pkfma(w2[6], sp(v6), uA);                                           \
        uB = pkfma(w2[7], sp(v7), uB);                                           \
        v2f u = uA + uB;                                                         \
        XG = TAB2[(NIDX) * 16 + l];             /* prefetch t+2 */               \
        /* sigma path (trans pipe), independent of the rational-tanh chain */    \
        float ex = __builtin_amdgcn_exp2f(u.x);                                  \
        float ey = __builtin_amdgcn_exp2f(u.y);                                  \
        float sx = __builtin_amdgcn_rcpf(1.0f + ex);                             \
        float sy = __builtin_amdgcn_rcpf(1.0f + ey);                             \
        /* rational tanh for g (s1 .x holds raw pre); s0 result discarded */     \
        float tg = tanh_f32(u.x);                                                \
        float ax = is1 ? tg : sx;   /* s0: sig(i);  s1: tanh(g) */               \
        float ay = sy;              /* s0: sig(f);  s1: sig(o)  */               \
        float pLo = dppf<DPP_ROR8>(ax);                                          \
        float pHi = dppf<DPP_ROR8>(ay);                                          \
        float IG  = ax * pLo;           /* sig(i)*tanh(g), both lanes */         \
        float F   = is0 ? ay : pHi;     /* sig(f) */                             \
        float O   = is0 ? pHi : ay;     /* sig(o) */                             \
        c  = __builtin_fmaf(F, c, IG);                                           \
        hn = O * tanh_f32(c);                                                    \
    } while (0)

    for (int t = 0; t < TT; t += 4) {
        const int nb = (t + 8 < TT) ? (t / 4 + 2) : 0;  // clamp tail prefetch
        int4 iN = *(const int4*)(xrow + nb * 4);
        STEP(xg0, iA.z);
        STEP(xg1, iA.w);
        STEP(xg0, iB.x);
        STEP(xg1, iB.y);
        iA = iB; iB = iN;
    }
#undef STEP

    // ---- head: out[b] = 0.5 + 0.5*tanh(0.5*(h.W_cls + b_cls)) ----
    // Lane l==0: hn=h_0, v_m=h_m -> identical summation/algorithm to R2-R5.
    {
        float v1 = dppf<DPP_XOR1>(hn);
        float v2 = dppf<DPP_XOR2>(hn);
        float v3 = dppf<DPP_XOR3>(hn);
        float v4 = dppf<DPP_ROR4>(hn);
        float v5 = dppf<DPP_XOR1>(v4);
        float v6 = dppf<DPP_XOR2>(v4);
        float v7 = dppf<DPP_XOR3>(v4);
        if (l == 0) {
            float z = b_cls[0]
                + hn * W_cls[0] + v1 * W_cls[1] + v2 * W_cls[2] + v3 * W_cls[3]
                + v4 * W_cls[4] + v5 * W_cls[5] + v6 * W_cls[6] + v7 * W_cls[7];
            out[b] = __builtin_fmaf(0.5f, tanh_f32(0.5f * z), 0.5f);
        }
    }
}

extern "C" void kernel_launch(void* const* d_in, const int* in_sizes, int n_in,
                              void* d_out, int out_size, void* d_ws, size_t ws_size,
                              hipStream_t stream)
{
    (void)in_sizes; (void)n_in; (void)d_ws; (void)ws_size; (void)out_size;
    const int*   x     = (const int*)  d_in[0];
    const float* emb   = (const float*)d_in[1];
    const float* W_ih  = (const float*)d_in[2];
    const float* W_hh  = (const float*)d_in[3];
    const float* b_ih  = (const float*)d_in[4];
    const float* b_hh  = (const float*)d_in[5];
    const float* W_cls = (const float*)d_in[6];
    const float* b_cls = (const float*)d_in[7];
    float* out = (float*)d_out;

    const int lds_bytes = NV * 16 * 8;  // 128000 <= 163840 (gfx950 opt-in)
    hipFuncSetAttribute((const void*)lstm_fused,
                        hipFuncAttributeMaxDynamicSharedMemorySize, lds_bytes);

    lstm_fused<<<dim3(256), dim3(256), lds_bytes, stream>>>(
        x, emb, W_ih, W_hh, b_ih, b_hh, W_cls, b_cls, out);
}